// Round 1
// baseline (77.671 us; speedup 1.0000x reference)
//
#include <hip/hip_runtime.h>
#include <math.h>

#define FFT_N   8192
#define LOGN    13
#define NROWS   512
#define THREADS 512
#define NBUT    (FFT_N / 2)
#define PULSE_THR 0.01f

// One block per row. LDS = re[8192]+im[8192] = 64 KB exactly.
__global__ __launch_bounds__(THREADS) void pulse_row_kernel(
    const float* __restrict__ pred,    // NROWS x FFT_N
    const float* __restrict__ label,   // NROWS x 2*FFT_N
    float* __restrict__ mse_per)       // NROWS
{
    __shared__ float re[FFT_N];
    __shared__ float im[FFT_N];

    const int row  = blockIdx.x;
    const int tid  = threadIdx.x;
    const int lane = tid & 63;
    const int wid  = tid >> 6;

    const float* lab_r = label + (size_t)row * (2 * FFT_N);
    const float* lab_i = lab_r + FFT_N;

    // ---------- Phase 0: first/last pulse window from labels ----------
    // (done before FFT so re[]/im[] can be used as reduction scratch)
    float minr = 1e9f, maxr = -1.f, mini = 1e9f, maxi = -1.f;
    for (int n = tid; n < FFT_N; n += THREADS) {
        float lr = lab_r[n], li = lab_i[n];
        float fn = (float)n;
        if (fabsf(lr) > PULSE_THR) { minr = fminf(minr, fn); maxr = fmaxf(maxr, fn); }
        if (fabsf(li) > PULSE_THR) { mini = fminf(mini, fn); maxi = fmaxf(maxi, fn); }
    }
    #pragma unroll
    for (int off = 32; off > 0; off >>= 1) {
        minr = fminf(minr, __shfl_down(minr, off));
        maxr = fmaxf(maxr, __shfl_down(maxr, off));
        mini = fminf(mini, __shfl_down(mini, off));
        maxi = fmaxf(maxi, __shfl_down(maxi, off));
    }
    if (lane == 0) {
        re[wid * 4 + 0] = minr; re[wid * 4 + 1] = maxr;
        re[wid * 4 + 2] = mini; re[wid * 4 + 3] = maxi;
    }
    __syncthreads();
    if (tid == 0) {
        float a = 1e9f, b = -1.f, c = 1e9f, d = -1.f;
        for (int w = 0; w < THREADS / 64; ++w) {
            a = fminf(a, re[w * 4 + 0]); b = fmaxf(b, re[w * 4 + 1]);
            c = fminf(c, re[w * 4 + 2]); d = fmaxf(d, re[w * 4 + 3]);
        }
        // reference semantics: empty mask -> (0, N-1) per component
        int fr  = (a > 1e8f) ? 0 : (int)a;
        int lr_ = (b < 0.f) ? (FFT_N - 1) : (int)b;
        int fi  = (c > 1e8f) ? 0 : (int)c;
        int li_ = (d < 0.f) ? (FFT_N - 1) : (int)d;
        im[0] = (float)min(fr, fi);
        im[1] = (float)max(lr_, li_);
    }
    __syncthreads();
    const int first = (int)im[0];
    const int last  = (int)im[1];
    __syncthreads();

    // ---------- Phase 1: load prediction as complex ----------
    const float* x = pred + (size_t)row * FFT_N;
    for (int i = tid; i < FFT_N; i += THREADS) {
        re[i] = x[i];
        im[i] = 0.f;
    }
    __syncthreads();

    // ---------- Forward DIF FFT: natural in -> bit-reversed out ----------
    for (int s = LOGN; s >= 1; --s) {
        const int half = 1 << (s - 1);
        for (int t = tid; t < NBUT; t += THREADS) {
            const int j   = t & (half - 1);
            const int grp = t >> (s - 1);
            const int i1  = (grp << s) + j;
            const int i2  = i1 + half;
            float ur = re[i1], ui = im[i1];
            float vr = re[i2], vi = im[i2];
            float ang = -(float)M_PI * (float)j / (float)half;  // -2*pi*j/m
            float sn, c;
            __sincosf(ang, &sn, &c);
            float dr = ur - vr, di = ui - vi;
            re[i1] = ur + vr;
            im[i1] = ui + vi;
            re[i2] = dr * c - di * sn;
            im[i2] = dr * sn + di * c;
        }
        __syncthreads();
    }

    // ---------- Spectral mask H (applied in bit-reversed order) ----------
    for (int p = tid; p < FFT_N; p += THREADS) {
        unsigned k = __brev((unsigned)p) >> (32 - LOGN);
        float f = (k < FFT_N / 2) ? 0.f : ((k == FFT_N / 2) ? 1.f : 2.f);
        re[p] *= f;
        im[p] *= f;
    }
    __syncthreads();

    // ---------- Inverse DIT FFT: bit-reversed in -> natural out ----------
    for (int s = 1; s <= LOGN; ++s) {
        const int half = 1 << (s - 1);
        for (int t = tid; t < NBUT; t += THREADS) {
            const int j   = t & (half - 1);
            const int grp = t >> (s - 1);
            const int i1  = (grp << s) + j;
            const int i2  = i1 + half;
            float ang = (float)M_PI * (float)j / (float)half;   // +2*pi*j/m
            float sn, c;
            __sincosf(ang, &sn, &c);
            float ur = re[i1], ui = im[i1];
            float vr0 = re[i2], vi0 = im[i2];
            float vr = vr0 * c - vi0 * sn;
            float vi = vr0 * sn + vi0 * c;
            re[i1] = ur + vr;
            im[i1] = ui + vi;
            re[i2] = ur - vr;
            im[i2] = ui - vi;
        }
        __syncthreads();
    }

    // ---------- Phase 2: accumulate the four MSE terms ----------
    float s0 = 0.f, s1 = 0.f, s2 = 0.f, s3 = 0.f;
    const float invN = 1.0f / (float)FFT_N;
    for (int n = tid; n < FFT_N; n += THREADS) {
        float pr = re[n] * invN;  // ifft scale
        float pi = im[n] * invN;
        float lr = lab_r[n], li = lab_i[n];
        float dr = pr - lr, di = pi - li;
        s0 += dr * dr;
        s1 += di * di;
        float dint = (pr * pr + pi * pi) - (lr * lr + li * li);
        s2 += dint * dint;
        if (n >= first && n < last) {
            float dph = atan2f(pi, pr) - atan2f(li, lr);
            s3 += dph * dph;
        }
    }
    __syncthreads();   // re[]/im[] now dead -> reuse re[] as scratch
    #pragma unroll
    for (int off = 32; off > 0; off >>= 1) {
        s0 += __shfl_down(s0, off);
        s1 += __shfl_down(s1, off);
        s2 += __shfl_down(s2, off);
        s3 += __shfl_down(s3, off);
    }
    if (lane == 0) {
        re[wid * 4 + 0] = s0; re[wid * 4 + 1] = s1;
        re[wid * 4 + 2] = s2; re[wid * 4 + 3] = s3;
    }
    __syncthreads();
    if (tid == 0) {
        float t0 = 0, t1 = 0, t2 = 0, t3 = 0;
        for (int w = 0; w < THREADS / 64; ++w) {
            t0 += re[w * 4 + 0]; t1 += re[w * 4 + 1];
            t2 += re[w * 4 + 2]; t3 += re[w * 4 + 3];
        }
        // mse_per = (sum of all four sums) / N / MSE_W_SUM(=4)
        mse_per[row] = (t0 + t1 + t2 + t3) * (invN * 0.25f);
    }
}

__global__ __launch_bounds__(512) void pulse_final_kernel(
    const float* __restrict__ mse_per, float* __restrict__ out)
{
    const int tid = threadIdx.x;
    double v = 0.0;
    if (tid < NROWS) {
        v = (double)(NROWS - tid) * (double)mse_per[tid];
    }
    #pragma unroll
    for (int off = 32; off > 0; off >>= 1) v += __shfl_down(v, off);
    __shared__ double lds[8];
    const int lane = tid & 63, wid = tid >> 6;
    if (lane == 0) lds[wid] = v;
    __syncthreads();
    if (tid == 0) {
        double t = 0.0;
        for (int i = 0; i < 8; ++i) t += lds[i];
        out[0] = (float)(t / (double)NROWS);
    }
}

extern "C" void kernel_launch(void* const* d_in, const int* in_sizes, int n_in,
                              void* d_out, int out_size, void* d_ws, size_t ws_size,
                              hipStream_t stream) {
    const float* pred  = (const float*)d_in[0];   // (512, 8192) f32
    const float* label = (const float*)d_in[1];   // (512, 16384) f32
    // d_in[2] spectrogram, d_in[3] header: unused by the loss value
    float* mse_per = (float*)d_ws;                // 512 floats of scratch
    float* out     = (float*)d_out;               // 1 float

    pulse_row_kernel<<<NROWS, THREADS, 0, stream>>>(pred, label, mse_per);
    pulse_final_kernel<<<1, 512, 0, stream>>>(mse_per, out);
}

// Round 2
// 45.531 us; speedup vs baseline: 1.7059x; 1.7059x over previous
//
#include <hip/hip_runtime.h>
#include <math.h>

#define NROWS   512
#define FFT_N   8192
#define THREADS 512
#define PULSE_THR 0.01f

typedef float2 cpx;

__device__ __forceinline__ cpx cadd(cpx a, cpx b){ return make_float2(a.x+b.x, a.y+b.y); }
__device__ __forceinline__ cpx csub(cpx a, cpx b){ return make_float2(a.x-b.x, a.y-b.y); }
__device__ __forceinline__ cpx cmul(cpx a, cpx b){
    return make_float2(fmaf(a.x, b.x, -(a.y*b.y)), fmaf(a.x, b.y, a.y*b.x));
}
__device__ __forceinline__ cpx cmuli(cpx a){ return make_float2(-a.y, a.x); }   // i*a
// e^{2*pi*i*rev} via native v_sin/v_cos (input in revolutions)
__device__ __forceinline__ cpx twf(float rev){
    return make_float2(__builtin_amdgcn_cosf(rev), __builtin_amdgcn_sinf(rev));
}
// LDS slot swizzle: XOR bits 7:4 into 3:0 so contiguous-16-per-thread reads
// spread across bank pairs (else 32-way conflict in the register tail).
__device__ __forceinline__ int slotf(int e){ return e ^ ((e >> 4) & 15); }

// fast atan2: octant reduction + Abramowitz-Stegun poly, |err| ~1e-5 rad
__device__ __forceinline__ float fast_atan2(float y, float x){
    float ax = fabsf(x), ay = fabsf(y);
    float mx = fmaxf(ax, ay), mn = fminf(ax, ay);
    float a  = mn * __builtin_amdgcn_rcpf(mx);
    if (mx == 0.0f) a = 0.0f;
    float s = a * a;
    float p = fmaf(s, fmaf(s, fmaf(s, fmaf(s, 0.0208351f, -0.085133f),
                                   0.180141f), -0.3302995f), 0.9998660f);
    p = p * a;
    if (ay > ax)   p = 1.57079632679f - p;
    if (x < 0.0f)  p = 3.14159265359f - p;
    return (y < 0.0f) ? -p : p;
}

// ---- forward DIF radix-4 stage (in-place over swizzled LDS) ----
template<int L>
__device__ __forceinline__ void fwd_stage(cpx* s, int tid){
    constexpr int q = L / 4;
    #pragma unroll
    for (int u = 0; u < 4; ++u){
        int t = tid + THREADS * u;
        int j = t & (q - 1);
        int base = ((t & ~(q - 1)) << 2) + j;
        cpx x0 = s[slotf(base)];
        cpx x1 = s[slotf(base + q)];
        cpx x2 = s[slotf(base + 2*q)];
        cpx x3 = s[slotf(base + 3*q)];
        float rev = -(float)j * (1.0f / (float)L);
        cpx w1 = twf(rev);
        cpx w2 = cmul(w1, w1);
        cpx w3 = cmul(w2, w1);
        cpx a = cadd(x0, x2), b = csub(x0, x2);
        cpx c = cadd(x1, x3), d = csub(x1, x3);
        s[slotf(base)]       = cadd(a, c);
        s[slotf(base + q)]   = cmul(csub(b, cmuli(d)), w1);
        s[slotf(base + 2*q)] = cmul(csub(a, c), w2);
        s[slotf(base + 3*q)] = cmul(cadd(b, cmuli(d)), w3);
    }
}

// ---- inverse DIT radix-4 stage (no 1/4; global 1/N applied in epilogue) ----
template<int L>
__device__ __forceinline__ void inv_stage(cpx* s, int tid){
    constexpr int q = L / 4;
    #pragma unroll
    for (int u = 0; u < 4; ++u){
        int t = tid + THREADS * u;
        int j = t & (q - 1);
        int base = ((t & ~(q - 1)) << 2) + j;
        float rev = (float)j * (1.0f / (float)L);
        cpx w1 = twf(rev);
        cpx w2 = cmul(w1, w1);
        cpx w3 = cmul(w2, w1);
        cpx z0 = s[slotf(base)];
        cpx z1 = cmul(s[slotf(base + q)],   w1);
        cpx z2 = cmul(s[slotf(base + 2*q)], w2);
        cpx z3 = cmul(s[slotf(base + 3*q)], w3);
        cpx a = cadd(z0, z2), b = csub(z0, z2);
        cpx c = cadd(z1, z3), d = csub(z1, z3);
        s[slotf(base)]       = cadd(a, c);
        s[slotf(base + q)]   = cadd(b, cmuli(d));
        s[slotf(base + 2*q)] = csub(a, c);
        s[slotf(base + 3*q)] = csub(b, cmuli(d));
    }
}

__global__ __launch_bounds__(THREADS, 4) void pulse_row_kernel(
    const float* __restrict__ pred,
    const float* __restrict__ label,
    float* __restrict__ mse_per)
{
    __shared__ cpx   sdat[FFT_N];          // 64 KB
    __shared__ int   sred[8][4];
    __shared__ float swsum[8];
    __shared__ int   s_first, s_last;

    const int row  = blockIdx.x;
    const int tid  = threadIdx.x;
    const int lane = tid & 63;
    const int wid  = tid >> 6;

    const float* lab_r = label + (size_t)row * (2 * FFT_N);
    const float* lab_i = lab_r + FFT_N;

    // ---------- Phase 0: pulse window from labels (float4 loads) ----------
    int minr = FFT_N, maxr = -1, mini = FFT_N, maxi = -1;
    const float4* lr4 = (const float4*)lab_r;
    const float4* li4 = (const float4*)lab_i;
    #pragma unroll
    for (int it = 0; it < 4; ++it){
        int idx = tid + THREADS * it;
        float4 a = lr4[idx];
        float4 b = li4[idx];
        int n0 = idx << 2;
        if (fabsf(a.x) > PULSE_THR){ minr = min(minr, n0);   maxr = max(maxr, n0);   }
        if (fabsf(a.y) > PULSE_THR){ minr = min(minr, n0+1); maxr = max(maxr, n0+1); }
        if (fabsf(a.z) > PULSE_THR){ minr = min(minr, n0+2); maxr = max(maxr, n0+2); }
        if (fabsf(a.w) > PULSE_THR){ minr = min(minr, n0+3); maxr = max(maxr, n0+3); }
        if (fabsf(b.x) > PULSE_THR){ mini = min(mini, n0);   maxi = max(maxi, n0);   }
        if (fabsf(b.y) > PULSE_THR){ mini = min(mini, n0+1); maxi = max(maxi, n0+1); }
        if (fabsf(b.z) > PULSE_THR){ mini = min(mini, n0+2); maxi = max(maxi, n0+2); }
        if (fabsf(b.w) > PULSE_THR){ mini = min(mini, n0+3); maxi = max(maxi, n0+3); }
    }
    #pragma unroll
    for (int off = 32; off; off >>= 1){
        minr = min(minr, __shfl_down(minr, off));
        maxr = max(maxr, __shfl_down(maxr, off));
        mini = min(mini, __shfl_down(mini, off));
        maxi = max(maxi, __shfl_down(maxi, off));
    }
    if (lane == 0){ sred[wid][0]=minr; sred[wid][1]=maxr; sred[wid][2]=mini; sred[wid][3]=maxi; }
    __syncthreads();
    if (tid == 0){
        int a = FFT_N, b = -1, c = FFT_N, d = -1;
        for (int w = 0; w < 8; ++w){
            a = min(a, sred[w][0]); b = max(b, sred[w][1]);
            c = min(c, sred[w][2]); d = max(d, sred[w][3]);
        }
        int fr  = (a == FFT_N) ? 0 : a;
        int lr_ = (b < 0) ? (FFT_N - 1) : b;
        int fi  = (c == FFT_N) ? 0 : c;
        int li_ = (d < 0) ? (FFT_N - 1) : d;
        s_first = min(fr, fi);
        s_last  = max(lr_, li_);
    }

    // ---------- Forward stage 0 (L=8192) fused with real-input load ----------
    const float* x = pred + (size_t)row * FFT_N;
    #pragma unroll
    for (int u = 0; u < 4; ++u){
        int j = tid + THREADS * u;               // j in [0,2048)
        float x0 = x[j], x1 = x[j+2048], x2 = x[j+4096], x3 = x[j+6144];
        float a = x0 + x2, b = x0 - x2, c = x1 + x3, d = x1 - x3;
        float rev = -(float)j * (1.0f / 8192.0f);
        cpx w1 = twf(rev);
        cpx w2 = cmul(w1, w1);
        cpx w3 = cmul(w2, w1);
        sdat[slotf(j)]        = make_float2(a + c, 0.0f);
        sdat[slotf(j + 2048)] = cmul(make_float2(b, -d), w1);      // (b - i d) w
        sdat[slotf(j + 4096)] = make_float2((a - c) * w2.x, (a - c) * w2.y);
        sdat[slotf(j + 6144)] = cmul(make_float2(b,  d), w3);      // (b + i d) w^3
    }
    __syncthreads();
    fwd_stage<2048>(sdat, tid); __syncthreads();
    fwd_stage<512>(sdat, tid);  __syncthreads();
    fwd_stage<128 >(sdat, tid); __syncthreads();
    fwd_stage<32  >(sdat, tid); __syncthreads();

    // ---------- Register tail: L=8, L=2, mask, inv L=2, inv L=8 ----------
    {
        cpx v[16];
        const int base16 = tid << 4;
        #pragma unroll
        for (int c = 0; c < 16; ++c) v[c] = sdat[slotf(base16 + c)];

        const float S2 = 0.70710678118654752f;
        // forward radix-4, L=8 (q=2): twiddles are constants
        #pragma unroll
        for (int b = 0; b < 16; b += 8){
            #pragma unroll
            for (int j = 0; j < 2; ++j){
                cpx x0=v[b+j], x1=v[b+j+2], x2=v[b+j+4], x3=v[b+j+6];
                cpx a  = cadd(x0,x2), bb = csub(x0,x2);
                cpx cc = cadd(x1,x3), d  = csub(x1,x3);
                cpx z0 = cadd(a, cc);
                cpx z1 = csub(bb, cmuli(d));
                cpx z2 = csub(a, cc);
                cpx z3 = cadd(bb, cmuli(d));
                if (j == 1){
                    z1 = cmul(z1, make_float2( S2, -S2));   // W8
                    z2 = make_float2(z2.y, -z2.x);          // * W8^2 = -i
                    z3 = cmul(z3, make_float2(-S2, -S2));   // W8^3
                }
                v[b+j]=z0; v[b+j+2]=z1; v[b+j+4]=z2; v[b+j+6]=z3;
            }
        }
        // forward radix-2, L=2
        #pragma unroll
        for (int i = 0; i < 16; i += 2){
            cpx x0 = v[i], x1 = v[i+1];
            v[i]   = cadd(x0, x1);
            v[i+1] = csub(x0, x1);
        }
        // spectral mask in permuted domain: freq k>=N/2 <=> position odd.
        // even pos -> 0 ; odd pos -> x2 ; global pos 1 (k==N/2) -> x1.
        #pragma unroll
        for (int c = 0; c < 16; c += 2) v[c] = make_float2(0.0f, 0.0f);
        #pragma unroll
        for (int c = 1; c < 16; c += 2){ v[c].x *= 2.0f; v[c].y *= 2.0f; }
        if (tid == 0){ v[1].x *= 0.5f; v[1].y *= 0.5f; }
        // inverse radix-2, L=2
        #pragma unroll
        for (int i = 0; i < 16; i += 2){
            cpx z0 = v[i], z1 = v[i+1];
            v[i]   = cadd(z0, z1);
            v[i+1] = csub(z0, z1);
        }
        // inverse radix-4, L=8: conj twiddles
        #pragma unroll
        for (int b = 0; b < 16; b += 8){
            #pragma unroll
            for (int j = 0; j < 2; ++j){
                cpx z0=v[b+j], z1=v[b+j+2], z2=v[b+j+4], z3=v[b+j+6];
                if (j == 1){
                    z1 = cmul(z1, make_float2( S2,  S2));   // conj W8
                    z2 = cmuli(z2);                          // conj W8^2 = +i
                    z3 = cmul(z3, make_float2(-S2,  S2));   // conj W8^3
                }
                cpx a  = cadd(z0,z2), bb = csub(z0,z2);
                cpx cc = cadd(z1,z3), d  = csub(z1,z3);
                v[b+j]   = cadd(a, cc);
                v[b+j+2] = cadd(bb, cmuli(d));
                v[b+j+4] = csub(a, cc);
                v[b+j+6] = csub(bb, cmuli(d));
            }
        }
        #pragma unroll
        for (int c = 0; c < 16; ++c) sdat[slotf(base16 + c)] = v[c];
    }
    __syncthreads();

    inv_stage<32  >(sdat, tid); __syncthreads();
    inv_stage<128 >(sdat, tid); __syncthreads();
    inv_stage<512 >(sdat, tid); __syncthreads();
    inv_stage<2048>(sdat, tid); __syncthreads();

    // ---------- Final inverse stage (L=8192) fused with epilogue ----------
    const int first = s_first;
    const int last  = s_last;
    const float invN = 1.0f / 8192.0f;
    float s0 = 0.f, s1 = 0.f, s2 = 0.f, s3 = 0.f;
    #pragma unroll
    for (int u = 0; u < 4; ++u){
        int j = tid + THREADS * u;
        float rev = (float)j * (1.0f / 8192.0f);
        cpx w1 = twf(rev);
        cpx w2 = cmul(w1, w1);
        cpx w3 = cmul(w2, w1);
        cpx z0 = sdat[slotf(j)];
        cpx z1 = cmul(sdat[slotf(j + 2048)], w1);
        cpx z2 = cmul(sdat[slotf(j + 4096)], w2);
        cpx z3 = cmul(sdat[slotf(j + 6144)], w3);
        cpx a = cadd(z0, z2), b = csub(z0, z2);
        cpx c = cadd(z1, z3), d = csub(z1, z3);
        cpx ys[4];
        ys[0] = cadd(a, c);
        ys[1] = cadd(b, cmuli(d));
        ys[2] = csub(a, c);
        ys[3] = csub(b, cmuli(d));
        #pragma unroll
        for (int m = 0; m < 4; ++m){
            int n = j + 2048 * m;
            float pr = ys[m].x * invN, pi = ys[m].y * invN;
            float lr = lab_r[n], li = lab_i[n];
            float dr = pr - lr, di = pi - li;
            s0 = fmaf(dr, dr, s0);
            s1 = fmaf(di, di, s1);
            float pint = fmaf(pr, pr, pi * pi);
            float lint = fmaf(lr, lr, li * li);
            float dint = pint - lint;
            s2 = fmaf(dint, dint, s2);
            if (n >= first && n < last){
                float dph = fast_atan2(pi, pr) - fast_atan2(li, lr);
                s3 = fmaf(dph, dph, s3);
            }
        }
    }
    float tot = s0 + s1 + s2 + s3;
    #pragma unroll
    for (int off = 32; off; off >>= 1) tot += __shfl_down(tot, off);
    if (lane == 0) swsum[wid] = tot;
    __syncthreads();
    if (tid == 0){
        float t = 0.f;
        for (int w = 0; w < 8; ++w) t += swsum[w];
        mse_per[row] = t * (invN * 0.25f);   // /N /MSE_W_SUM
    }
}

__global__ __launch_bounds__(512) void pulse_final_kernel(
    const float* __restrict__ mse_per, float* __restrict__ out)
{
    const int tid = threadIdx.x;
    double v = 0.0;
    if (tid < NROWS) v = (double)(NROWS - tid) * (double)mse_per[tid];
    #pragma unroll
    for (int off = 32; off; off >>= 1) v += __shfl_down(v, off);
    __shared__ double lds[8];
    const int lane = tid & 63, wid = tid >> 6;
    if (lane == 0) lds[wid] = v;
    __syncthreads();
    if (tid == 0){
        double t = 0.0;
        for (int i = 0; i < 8; ++i) t += lds[i];
        out[0] = (float)(t / (double)NROWS);
    }
}

extern "C" void kernel_launch(void* const* d_in, const int* in_sizes, int n_in,
                              void* d_out, int out_size, void* d_ws, size_t ws_size,
                              hipStream_t stream) {
    const float* pred  = (const float*)d_in[0];   // (512, 8192)  f32
    const float* label = (const float*)d_in[1];   // (512, 16384) f32
    float* mse_per = (float*)d_ws;                // 512 floats scratch
    float* out     = (float*)d_out;               // 1 float

    pulse_row_kernel<<<NROWS, THREADS, 0, stream>>>(pred, label, mse_per);
    pulse_final_kernel<<<1, 512, 0, stream>>>(mse_per, out);
}

// Round 3
// 29.807 us; speedup vs baseline: 2.6058x; 1.5275x over previous
//
#include <hip/hip_runtime.h>

#define NROWS   512
#define FFT_M   4096      // half-length complex FFT (N = 8192 real points)
#define THREADS 512
#define PULSE_THR 0.01f

typedef float2 cpx;

__device__ __forceinline__ cpx cadd(cpx a, cpx b){ return make_float2(a.x+b.x, a.y+b.y); }
__device__ __forceinline__ cpx csub(cpx a, cpx b){ return make_float2(a.x-b.x, a.y-b.y); }
__device__ __forceinline__ cpx cmul(cpx a, cpx b){
    return make_float2(fmaf(a.x, b.x, -(a.y*b.y)), fmaf(a.x, b.y, a.y*b.x));
}
__device__ __forceinline__ cpx cmuli(cpx a){ return make_float2(-a.y, a.x); }   // i*a
// e^{2*pi*i*rev} via native v_sin/v_cos (argument in revolutions)
__device__ __forceinline__ cpx twf(float rev){
    return make_float2(__builtin_amdgcn_cosf(rev), __builtin_amdgcn_sinf(rev));
}
// LDS slot swizzle: fold bits 4-11 into 0-3 to spread strided accesses
__device__ __forceinline__ int slotf(int e){ return e ^ ((e >> 4) & 15) ^ ((e >> 8) & 15); }
// 5-digit base-4 reversal of a 10-bit index
__device__ __forceinline__ int rev5(int k){
    unsigned r = __brev((unsigned)k) >> 22;                 // 10-bit bit reversal
    return (int)(((r & 0x155u) << 1) | ((r & 0x2AAu) >> 1)); // swap bit pairs
}

// fast atan2: octant reduction + poly, |err| ~1e-5 rad
__device__ __forceinline__ float fast_atan2(float y, float x){
    float ax = fabsf(x), ay = fabsf(y);
    float mx = fmaxf(ax, ay), mn = fminf(ax, ay);
    float a  = mn * __builtin_amdgcn_rcpf(mx);
    if (mx == 0.0f) a = 0.0f;
    float s = a * a;
    float p = fmaf(s, fmaf(s, fmaf(s, fmaf(s, 0.0208351f, -0.085133f),
                                   0.180141f), -0.3302995f), 0.9998660f);
    p = p * a;
    if (ay > ax)   p = 1.57079632679f - p;
    if (x < 0.0f)  p = 3.14159265359f - p;
    return (y < 0.0f) ? -p : p;
}

// forward DIF radix-4 LDS stage (2 butterflies/thread, M=4096)
template<int L>
__device__ __forceinline__ void fwd_stage(cpx* s, int tid){
    constexpr int q = L / 4;
    #pragma unroll
    for (int u = 0; u < 2; ++u){
        int t = tid + THREADS * u;                  // 0..1023
        int j = t & (q - 1);
        int base = ((t & ~(q - 1)) << 2) + j;
        cpx x0 = s[slotf(base)];
        cpx x1 = s[slotf(base + q)];
        cpx x2 = s[slotf(base + 2*q)];
        cpx x3 = s[slotf(base + 3*q)];
        float rev = -(float)j * (1.0f / (float)L);
        cpx w1 = twf(rev);
        cpx w2 = cmul(w1, w1);
        cpx w3 = cmul(w2, w1);
        cpx a = cadd(x0, x2), b = csub(x0, x2);
        cpx c = cadd(x1, x3), d = csub(x1, x3);
        s[slotf(base)]       = cadd(a, c);
        s[slotf(base + q)]   = cmul(csub(b, cmuli(d)), w1);
        s[slotf(base + 2*q)] = cmul(csub(a, c), w2);
        s[slotf(base + 3*q)] = cmul(cadd(b, cmuli(d)), w3);
    }
}

// inverse DIT radix-4 LDS stage (unscaled)
template<int L>
__device__ __forceinline__ void inv_stage(cpx* s, int tid){
    constexpr int q = L / 4;
    #pragma unroll
    for (int u = 0; u < 2; ++u){
        int t = tid + THREADS * u;
        int j = t & (q - 1);
        int base = ((t & ~(q - 1)) << 2) + j;
        float rev = (float)j * (1.0f / (float)L);
        cpx w1 = twf(rev);
        cpx w2 = cmul(w1, w1);
        cpx w3 = cmul(w2, w1);
        cpx z0 = s[slotf(base)];
        cpx z1 = cmul(s[slotf(base + q)],   w1);
        cpx z2 = cmul(s[slotf(base + 2*q)], w2);
        cpx z3 = cmul(s[slotf(base + 3*q)], w3);
        cpx a = cadd(z0, z2), b = csub(z0, z2);
        cpx c = cadd(z1, z3), d = csub(z1, z3);
        s[slotf(base)]       = cadd(a, c);
        s[slotf(base + q)]   = cadd(b, cmuli(d));
        s[slotf(base + 2*q)] = csub(a, c);
        s[slotf(base + 3*q)] = csub(b, cmuli(d));
    }
}

// trivial radix-4 (w=1) butterflies on 4 contiguous values
__device__ __forceinline__ void fwd4(cpx* v){
    cpx a = cadd(v[0], v[2]), b = csub(v[0], v[2]);
    cpx c = cadd(v[1], v[3]), d = csub(v[1], v[3]);
    v[0] = cadd(a, c);
    v[1] = csub(b, cmuli(d));
    v[2] = csub(a, c);
    v[3] = cadd(b, cmuli(d));
}
__device__ __forceinline__ void inv4(cpx* v){
    cpx a = cadd(v[0], v[2]), b = csub(v[0], v[2]);
    cpx c = cadd(v[1], v[3]), d = csub(v[1], v[3]);
    v[0] = cadd(a, c);
    v[1] = cadd(b, cmuli(d));
    v[2] = csub(a, c);
    v[3] = csub(b, cmuli(d));
}

// Za = Z[k], Zb = Z[4096-k]  -->  Za = C[k], Zb = C[4096-k]
// C[k]  = e^{-i th} D - e^{+i th} E ;  C[kc] = e^{+i th} conj(D) + e^{-i th} conj(E)
// with E = (Za + conj Zb)/2, D = (Za - conj Zb)/2, th = 2 pi k / 8192
__device__ __forceinline__ void hpair(cpx& Za, cpx& Zb, float krev){
    cpx w  = twf(krev);                       // e^{+i th}
    cpx wc = make_float2(w.x, -w.y);          // e^{-i th}
    cpx E  = make_float2(0.5f*(Za.x + Zb.x), 0.5f*(Za.y - Zb.y));
    cpx D  = make_float2(0.5f*(Za.x - Zb.x), 0.5f*(Za.y + Zb.y));
    cpx Ck  = csub(cmul(wc, D), cmul(w, E));
    cpx Ckc = cadd(cmul(w, make_float2(D.x, -D.y)), cmul(wc, make_float2(E.x, -E.y)));
    Za = Ck; Zb = Ckc;
}

__global__ __launch_bounds__(THREADS, 4) void pulse_row_kernel(
    const float* __restrict__ pred,
    const float* __restrict__ label,
    float* __restrict__ mse_per)
{
    __shared__ cpx   sdat[FFT_M];          // 32 KB
    __shared__ int   sred[8][4];
    __shared__ float swsum[8];
    __shared__ int   s_first, s_last;
    __shared__ float s_mean;

    const int row  = blockIdx.x;
    const int tid  = threadIdx.x;
    const int lane = tid & 63;
    const int wid  = tid >> 6;

    const float* lab_r = label + (size_t)row * 16384;
    const float* lab_i = lab_r + 8192;

    // ---------- Phase 0: pulse-window scan over labels ----------
    int minr = 8192, maxr = -1, mini = 8192, maxi = -1;
    const float4* lr4 = (const float4*)lab_r;
    const float4* li4 = (const float4*)lab_i;
    #pragma unroll
    for (int it = 0; it < 4; ++it){
        int idx = tid + THREADS * it;
        float4 a = lr4[idx];
        float4 b = li4[idx];
        int n0 = idx << 2;
        if (fabsf(a.x) > PULSE_THR){ minr = min(minr, n0);   maxr = max(maxr, n0);   }
        if (fabsf(a.y) > PULSE_THR){ minr = min(minr, n0+1); maxr = max(maxr, n0+1); }
        if (fabsf(a.z) > PULSE_THR){ minr = min(minr, n0+2); maxr = max(maxr, n0+2); }
        if (fabsf(a.w) > PULSE_THR){ minr = min(minr, n0+3); maxr = max(maxr, n0+3); }
        if (fabsf(b.x) > PULSE_THR){ mini = min(mini, n0);   maxi = max(maxi, n0);   }
        if (fabsf(b.y) > PULSE_THR){ mini = min(mini, n0+1); maxi = max(maxi, n0+1); }
        if (fabsf(b.z) > PULSE_THR){ mini = min(mini, n0+2); maxi = max(maxi, n0+2); }
        if (fabsf(b.w) > PULSE_THR){ mini = min(mini, n0+3); maxi = max(maxi, n0+3); }
    }
    #pragma unroll
    for (int off = 32; off; off >>= 1){
        minr = min(minr, __shfl_down(minr, off));
        maxr = max(maxr, __shfl_down(maxr, off));
        mini = min(mini, __shfl_down(mini, off));
        maxi = max(maxi, __shfl_down(maxi, off));
    }
    if (lane == 0){ sred[wid][0]=minr; sred[wid][1]=maxr; sred[wid][2]=mini; sred[wid][3]=maxi; }

    // ---------- Load z[t] = x[2t] + i x[2t+1], fused fwd stage 0 (L=4096) ----------
    const float2* zin = (const float2*)(pred + (size_t)row * 8192);
    cpx zv[8];
    #pragma unroll
    for (int u = 0; u < 8; ++u) zv[u] = zin[tid + THREADS * u];
    #pragma unroll
    for (int b = 0; b < 2; ++b){
        int j = tid + THREADS * b;                 // 0..1023
        cpx z0 = zv[b], z1 = zv[b+2], z2 = zv[b+4], z3 = zv[b+6];
        cpx a = cadd(z0, z2), bb = csub(z0, z2);
        cpx c = cadd(z1, z3), d = csub(z1, z3);
        float rev = -(float)j * (1.0f / 4096.0f);
        cpx w1 = twf(rev);
        cpx w2 = cmul(w1, w1);
        cpx w3 = cmul(w2, w1);
        sdat[slotf(j)]        = cadd(a, c);
        sdat[slotf(j + 1024)] = cmul(csub(bb, cmuli(d)), w1);
        sdat[slotf(j + 2048)] = cmul(csub(a, c), w2);
        sdat[slotf(j + 3072)] = cmul(cadd(bb, cmuli(d)), w3);
    }
    __syncthreads();

    // window combine (thread 0) overlapped with next stage of other threads
    if (tid == 0){
        int a = 8192, b = -1, c = 8192, d = -1;
        for (int w = 0; w < 8; ++w){
            a = min(a, sred[w][0]); b = max(b, sred[w][1]);
            c = min(c, sred[w][2]); d = max(d, sred[w][3]);
        }
        int fr  = (a == 8192) ? 0 : a;
        int lr_ = (b < 0) ? 8191 : b;
        int fi  = (c == 8192) ? 0 : c;
        int li_ = (d < 0) ? 8191 : d;
        s_first = min(fr, fi);
        s_last  = max(lr_, li_);
    }

    fwd_stage<1024>(sdat, tid); __syncthreads();
    fwd_stage<256 >(sdat, tid); __syncthreads();
    fwd_stage<64  >(sdat, tid); __syncthreads();
    fwd_stage<16  >(sdat, tid); __syncthreads();

    // ---------- Fused: fwd L=4 tail + Z->C Hilbert pairing + inv L=4 ----------
    {
        int kA = (tid == 0) ? 0   : tid;           // group base freq (mod 1024)
        int kB = (tid == 0) ? 512 : 1024 - tid;
        int pA = rev5(kA) << 2;                    // 4 contiguous positions
        int pB = rev5(kB) << 2;
        cpx va[4], vb[4];
        #pragma unroll
        for (int m = 0; m < 4; ++m){ va[m] = sdat[slotf(pA+m)]; vb[m] = sdat[slotf(pB+m)]; }
        fwd4(va); fwd4(vb);                        // va[m] = Z[kA + 1024m]
        if (tid == 0){
            s_mean = (va[0].x + va[0].y) * (1.0f / 8192.0f);  // Z[0] -> mean(x)
            va[0] = make_float2(0.f, 0.f);                    // C[0] = 0
            va[2] = make_float2(va[2].y, -va[2].x);           // C[2048] = -i Z[2048]
            hpair(va[1], va[3], 1024.0f / 8192.0f);           // (1024, 3072)
            hpair(vb[0], vb[3],  512.0f / 8192.0f);           // (512, 3584)
            hpair(vb[1], vb[2], 1536.0f / 8192.0f);           // (1536, 2560)
        } else {
            #pragma unroll
            for (int m = 0; m < 4; ++m){
                float krev = (float)(tid + 1024*m) * (1.0f / 8192.0f);
                hpair(va[m], vb[3-m], krev);       // (k, 4096-k)
            }
        }
        inv4(va); inv4(vb);
        #pragma unroll
        for (int m = 0; m < 4; ++m){ sdat[slotf(pA+m)] = va[m]; sdat[slotf(pB+m)] = vb[m]; }
    }
    __syncthreads();

    inv_stage<16  >(sdat, tid); __syncthreads();
    inv_stage<64  >(sdat, tid); __syncthreads();
    inv_stage<256 >(sdat, tid); __syncthreads();
    inv_stage<1024>(sdat, tid); __syncthreads();

    // ---------- Final inverse stage (L=4096) fused with epilogue ----------
    const int   first = s_first;
    const int   last  = s_last;
    const float mean  = s_mean;
    const float invM  = 1.0f / 4096.0f;
    const float2* xr2 = (const float2*)(pred + (size_t)row * 8192);
    const float2* lr2 = (const float2*)lab_r;
    const float2* li2 = (const float2*)lab_i;
    float acc = 0.f;
    #pragma unroll
    for (int b = 0; b < 2; ++b){
        int j = tid + THREADS * b;
        float rev = (float)j * (1.0f / 4096.0f);
        cpx w1 = twf(rev);
        cpx w2 = cmul(w1, w1);
        cpx w3 = cmul(w2, w1);
        cpx z0 = sdat[slotf(j)];
        cpx z1 = cmul(sdat[slotf(j + 1024)], w1);
        cpx z2 = cmul(sdat[slotf(j + 2048)], w2);
        cpx z3 = cmul(sdat[slotf(j + 3072)], w3);
        cpx a = cadd(z0, z2), bb = csub(z0, z2);
        cpx c = cadd(z1, z3), d = csub(z1, z3);
        cpx outs[4];
        outs[0] = cadd(a, c);
        outs[1] = cadd(bb, cmuli(d));
        outs[2] = csub(a, c);
        outs[3] = csub(bb, cmuli(d));
        #pragma unroll
        for (int m = 0; m < 4; ++m){
            int t = j + 1024 * m;                  // c[t] = h[2t] + i h[2t+1]
            float2 xv  = xr2[t];
            float2 lrv = lr2[t];
            float2 liv = li2[t];
            float pi0 = outs[m].x * invM, pi1 = outs[m].y * invM;
            float pr0 = xv.x - mean,      pr1 = xv.y - mean;
            int n = 2 * t;
            {
                float dr = pr0 - lrv.x, di = pi0 - liv.x;
                acc = fmaf(dr, dr, acc);
                acc = fmaf(di, di, acc);
                float dint = fmaf(pr0, pr0, pi0*pi0) - fmaf(lrv.x, lrv.x, liv.x*liv.x);
                acc = fmaf(dint, dint, acc);
                if (n >= first && n < last){
                    float dph = fast_atan2(pi0, pr0) - fast_atan2(liv.x, lrv.x);
                    acc = fmaf(dph, dph, acc);
                }
            }
            {
                float dr = pr1 - lrv.y, di = pi1 - liv.y;
                acc = fmaf(dr, dr, acc);
                acc = fmaf(di, di, acc);
                float dint = fmaf(pr1, pr1, pi1*pi1) - fmaf(lrv.y, lrv.y, liv.y*liv.y);
                acc = fmaf(dint, dint, acc);
                if (n + 1 >= first && n + 1 < last){
                    float dph = fast_atan2(pi1, pr1) - fast_atan2(liv.y, lrv.y);
                    acc = fmaf(dph, dph, acc);
                }
            }
        }
    }
    #pragma unroll
    for (int off = 32; off; off >>= 1) acc += __shfl_down(acc, off);
    if (lane == 0) swsum[wid] = acc;
    __syncthreads();
    if (tid == 0){
        float t = 0.f;
        for (int w = 0; w < 8; ++w) t += swsum[w];
        mse_per[row] = t * (1.0f / 8192.0f) * 0.25f;   // /N /MSE_W_SUM
    }
}

__global__ __launch_bounds__(512) void pulse_final_kernel(
    const float* __restrict__ mse_per, float* __restrict__ out)
{
    const int tid = threadIdx.x;
    double v = 0.0;
    if (tid < NROWS) v = (double)(NROWS - tid) * (double)mse_per[tid];
    #pragma unroll
    for (int off = 32; off; off >>= 1) v += __shfl_down(v, off);
    __shared__ double lds[8];
    const int lane = tid & 63, wid = tid >> 6;
    if (lane == 0) lds[wid] = v;
    __syncthreads();
    if (tid == 0){
        double t = 0.0;
        for (int i = 0; i < 8; ++i) t += lds[i];
        out[0] = (float)(t / (double)NROWS);
    }
}

extern "C" void kernel_launch(void* const* d_in, const int* in_sizes, int n_in,
                              void* d_out, int out_size, void* d_ws, size_t ws_size,
                              hipStream_t stream) {
    const float* pred  = (const float*)d_in[0];   // (512, 8192)  f32
    const float* label = (const float*)d_in[1];   // (512, 16384) f32
    float* mse_per = (float*)d_ws;                // 512 floats scratch
    float* out     = (float*)d_out;               // 1 float

    pulse_row_kernel<<<NROWS, THREADS, 0, stream>>>(pred, label, mse_per);
    pulse_final_kernel<<<1, 512, 0, stream>>>(mse_per, out);
}

// Round 4
// 28.251 us; speedup vs baseline: 2.7493x; 1.0551x over previous
//
#include <hip/hip_runtime.h>

#define NROWS   512
#define THREADS 512
#define PULSE_THR 0.01f

typedef float2 cpx;

__device__ __forceinline__ cpx cadd(cpx a, cpx b){ return make_float2(a.x+b.x, a.y+b.y); }
__device__ __forceinline__ cpx csub(cpx a, cpx b){ return make_float2(a.x-b.x, a.y-b.y); }
__device__ __forceinline__ cpx cmul(cpx a, cpx b){
    return make_float2(fmaf(a.x, b.x, -(a.y*b.y)), fmaf(a.x, b.y, a.y*b.x));
}
__device__ __forceinline__ cpx cmuli(cpx a){ return make_float2(-a.y, a.x); }   // i*a
// e^{2*pi*i*rev} via native v_sin/v_cos (argument in revolutions)
__device__ __forceinline__ cpx twf(float rev){
    return make_float2(__builtin_amdgcn_cosf(rev), __builtin_amdgcn_sinf(rev));
}
// LDS slot swizzle (as R3): fold bits 4-11 into 0-3 to spread strided accesses
__device__ __forceinline__ int slotf(int e){ return e ^ ((e >> 4) & 15) ^ ((e >> 8) & 15); }
// base-8 digit reversal of a 9-bit index (3 digits) — involution
__device__ __forceinline__ int rev3(int t){ return ((t & 7) << 6) | (t & 0x38) | (t >> 6); }

// fast atan2: octant reduction + poly, |err| ~1e-5 rad
__device__ __forceinline__ float fast_atan2(float y, float x){
    float ax = fabsf(x), ay = fabsf(y);
    float mx = fmaxf(ax, ay), mn = fminf(ax, ay);
    float a  = mn * __builtin_amdgcn_rcpf(mx);
    if (mx == 0.0f) a = 0.0f;
    float s = a * a;
    float p = fmaf(s, fmaf(s, fmaf(s, fmaf(s, 0.0208351f, -0.085133f),
                                   0.180141f), -0.3302995f), 0.9998660f);
    p = p * a;
    if (ay > ax)   p = 1.57079632679f - p;
    if (x < 0.0f)  p = 3.14159265359f - p;
    return (y < 0.0f) ? -p : p;
}

// 8-point DFT, natural order in/out, W8 = e^{-2pi i/8}  (forward)
__device__ __forceinline__ void dft8_fwd(cpx* x){
    const float S = 0.70710678118654752f;
    cpx a0=cadd(x[0],x[4]), a1=cadd(x[1],x[5]), a2=cadd(x[2],x[6]), a3=cadd(x[3],x[7]);
    cpx b0=csub(x[0],x[4]), b1=csub(x[1],x[5]), b2=csub(x[2],x[6]), b3=csub(x[3],x[7]);
    cpx c0=cadd(a0,a2), c1=csub(a0,a2), c2=cadd(a1,a3), c3=csub(a1,a3);
    x[0]=cadd(c0,c2);
    x[4]=csub(c0,c2);
    x[2]=csub(c1,cmuli(c3));
    x[6]=cadd(c1,cmuli(c3));
    cpx t1 = make_float2(S*(b1.x+b1.y), S*(b1.y-b1.x));    // b1*W8
    cpx t2 = make_float2(b2.y, -b2.x);                     // b2*W8^2 = -i b2
    cpx t3 = make_float2(S*(b3.y-b3.x), -S*(b3.x+b3.y));   // b3*W8^3
    cpx d0=cadd(b0,t2), d1=csub(b0,t2), d2=cadd(t1,t3), d3=csub(t1,t3);
    x[1]=cadd(d0,d2);
    x[5]=csub(d0,d2);
    x[3]=csub(d1,cmuli(d3));
    x[7]=cadd(d1,cmuli(d3));
}
// 8-point inverse DFT (unnormalized), conj twiddles
__device__ __forceinline__ void dft8_inv(cpx* x){
    const float S = 0.70710678118654752f;
    cpx a0=cadd(x[0],x[4]), a1=cadd(x[1],x[5]), a2=cadd(x[2],x[6]), a3=cadd(x[3],x[7]);
    cpx b0=csub(x[0],x[4]), b1=csub(x[1],x[5]), b2=csub(x[2],x[6]), b3=csub(x[3],x[7]);
    cpx c0=cadd(a0,a2), c1=csub(a0,a2), c2=cadd(a1,a3), c3=csub(a1,a3);
    x[0]=cadd(c0,c2);
    x[4]=csub(c0,c2);
    x[2]=cadd(c1,cmuli(c3));
    x[6]=csub(c1,cmuli(c3));
    cpx t1 = make_float2(S*(b1.x-b1.y), S*(b1.y+b1.x));    // b1*conj(W8)
    cpx t2 = make_float2(-b2.y, b2.x);                     // +i b2
    cpx t3 = make_float2(-S*(b3.x+b3.y), S*(b3.x-b3.y));   // b3*conj(W8)^3
    cpx d0=cadd(b0,t2), d1=csub(b0,t2), d2=cadd(t1,t3), d3=csub(t1,t3);
    x[1]=cadd(d0,d2);
    x[5]=csub(d0,d2);
    x[3]=cadd(d1,cmuli(d3));
    x[7]=csub(d1,cmuli(d3));
}

// forward DIF radix-8 LDS stage: butterfly then twiddle W_L^{jm}
template<int L>
__device__ __forceinline__ void fwd_stage8(cpx* sd, int tid){
    constexpr int q = L / 8;
    const int j    = tid & (q - 1);
    const int base = ((tid & ~(q - 1)) << 3) + j;
    cpx v[8];
    #pragma unroll
    for (int m = 0; m < 8; ++m) v[m] = sd[slotf(base + m*q)];
    dft8_fwd(v);
    cpx w1 = twf(-(float)j * (1.0f/(float)L));
    cpx w2 = cmul(w1,w1), w3 = cmul(w2,w1), w4 = cmul(w2,w2);
    cpx w5 = cmul(w4,w1), w6 = cmul(w3,w3), w7 = cmul(w4,w3);
    v[1]=cmul(v[1],w1); v[2]=cmul(v[2],w2); v[3]=cmul(v[3],w3);
    v[4]=cmul(v[4],w4); v[5]=cmul(v[5],w5); v[6]=cmul(v[6],w6); v[7]=cmul(v[7],w7);
    #pragma unroll
    for (int m = 0; m < 8; ++m) sd[slotf(base + m*q)] = v[m];
}
// inverse DIT radix-8 LDS stage: twiddle W_L^{+jm} then inverse butterfly
template<int L>
__device__ __forceinline__ void inv_stage8(cpx* sd, int tid){
    constexpr int q = L / 8;
    const int j    = tid & (q - 1);
    const int base = ((tid & ~(q - 1)) << 3) + j;
    cpx v[8];
    #pragma unroll
    for (int m = 0; m < 8; ++m) v[m] = sd[slotf(base + m*q)];
    cpx w1 = twf((float)j * (1.0f/(float)L));
    cpx w2 = cmul(w1,w1), w3 = cmul(w2,w1), w4 = cmul(w2,w2);
    cpx w5 = cmul(w4,w1), w6 = cmul(w3,w3), w7 = cmul(w4,w3);
    v[1]=cmul(v[1],w1); v[2]=cmul(v[2],w2); v[3]=cmul(v[3],w3);
    v[4]=cmul(v[4],w4); v[5]=cmul(v[5],w5); v[6]=cmul(v[6],w6); v[7]=cmul(v[7],w7);
    dft8_inv(v);
    #pragma unroll
    for (int m = 0; m < 8; ++m) sd[slotf(base + m*q)] = v[m];
}

__global__ __launch_bounds__(THREADS, 4) void pulse_row_kernel(
    const float* __restrict__ pred,
    const float* __restrict__ label,
    float* __restrict__ mse_per)
{
    __shared__ cpx   sdat[4096];           // 32 KB
    __shared__ int   sred[8][4];
    __shared__ float swsum[8];
    __shared__ int   s_first, s_last;
    __shared__ float s_mean;

    const int row  = blockIdx.x;
    const int tid  = threadIdx.x;
    const int lane = tid & 63;
    const int wid  = tid >> 6;

    const float* lab_r = label + (size_t)row * 16384;
    const float* lab_i = lab_r + 8192;

    // ---------- Phase 0: pulse-window scan over labels ----------
    int minr = 8192, maxr = -1, mini = 8192, maxi = -1;
    const float4* lr4 = (const float4*)lab_r;
    const float4* li4 = (const float4*)lab_i;
    #pragma unroll
    for (int it = 0; it < 4; ++it){
        int idx = tid + THREADS * it;
        float4 a = lr4[idx];
        float4 b = li4[idx];
        int n0 = idx << 2;
        if (fabsf(a.x) > PULSE_THR){ minr = min(minr, n0);   maxr = max(maxr, n0);   }
        if (fabsf(a.y) > PULSE_THR){ minr = min(minr, n0+1); maxr = max(maxr, n0+1); }
        if (fabsf(a.z) > PULSE_THR){ minr = min(minr, n0+2); maxr = max(maxr, n0+2); }
        if (fabsf(a.w) > PULSE_THR){ minr = min(minr, n0+3); maxr = max(maxr, n0+3); }
        if (fabsf(b.x) > PULSE_THR){ mini = min(mini, n0);   maxi = max(maxi, n0);   }
        if (fabsf(b.y) > PULSE_THR){ mini = min(mini, n0+1); maxi = max(maxi, n0+1); }
        if (fabsf(b.z) > PULSE_THR){ mini = min(mini, n0+2); maxi = max(maxi, n0+2); }
        if (fabsf(b.w) > PULSE_THR){ mini = min(mini, n0+3); maxi = max(maxi, n0+3); }
    }
    #pragma unroll
    for (int off = 32; off; off >>= 1){
        minr = min(minr, __shfl_down(minr, off));
        maxr = max(maxr, __shfl_down(maxr, off));
        mini = min(mini, __shfl_down(mini, off));
        maxi = max(maxi, __shfl_down(maxi, off));
    }
    if (lane == 0){ sred[wid][0]=minr; sred[wid][1]=maxr; sred[wid][2]=mini; sred[wid][3]=maxi; }

    // ---------- Load z[t]=x[2t]+i x[2t+1] (kept in regs) + fused fwd L=4096 ----------
    const float2* zin = (const float2*)(pred + (size_t)row * 8192);
    cpx zv[8];
    #pragma unroll
    for (int u = 0; u < 8; ++u) zv[u] = zin[tid + THREADS * u];
    {
        cpx v[8];
        #pragma unroll
        for (int m = 0; m < 8; ++m) v[m] = zv[m];
        dft8_fwd(v);
        cpx w1 = twf(-(float)tid * (1.0f/4096.0f));
        cpx w2 = cmul(w1,w1), w3 = cmul(w2,w1), w4 = cmul(w2,w2);
        cpx w5 = cmul(w4,w1), w6 = cmul(w3,w3), w7 = cmul(w4,w3);
        v[1]=cmul(v[1],w1); v[2]=cmul(v[2],w2); v[3]=cmul(v[3],w3);
        v[4]=cmul(v[4],w4); v[5]=cmul(v[5],w5); v[6]=cmul(v[6],w6); v[7]=cmul(v[7],w7);
        #pragma unroll
        for (int m = 0; m < 8; ++m) sdat[slotf(tid + 512*m)] = v[m];
    }
    __syncthreads();

    if (tid == 0){
        int a = 8192, b = -1, c = 8192, d = -1;
        for (int w = 0; w < 8; ++w){
            a = min(a, sred[w][0]); b = max(b, sred[w][1]);
            c = min(c, sred[w][2]); d = max(d, sred[w][3]);
        }
        int fr  = (a == 8192) ? 0 : a;
        int lr_ = (b < 0) ? 8191 : b;
        int fi  = (c == 8192) ? 0 : c;
        int li_ = (d < 0) ? 8191 : d;
        s_first = min(fr, fi);
        s_last  = max(lr_, li_);
    }

    fwd_stage8<512>(sdat, tid); __syncthreads();
    fwd_stage8<64 >(sdat, tid); __syncthreads();

    // ---------- Middle: fwd L=8 (regs) + Hilbert Z->C pairing + inv L=8 (regs) ----------
    {
        const int s  = rev3(tid);            // own 8 freqs: k = a*512 + s
        const int sp = (512 - s) & 511;      // partner digit-group
        const int tp = rev3(sp);
        cpx va[8], vb[8];
        #pragma unroll
        for (int a = 0; a < 8; ++a) va[a] = sdat[slotf(8*tid + a)];
        #pragma unroll
        for (int a = 0; a < 8; ++a) vb[a] = sdat[slotf(8*tp  + a)];
        __syncthreads();                     // all reads before any writes
        dft8_fwd(va);
        dft8_fwd(vb);
        if (tid == 0){
            s_mean = (va[0].x + va[0].y) * (1.0f/8192.0f);   // Z[0] -> mean(x)
            #pragma unroll
            for (int i = 0; i < 8; ++i) vb[i] = va[(i + 1) & 7];  // kc=(8-a)*512 fix
        }
        cpx es = twf((float)s * (1.0f/8192.0f));
        // W16[a] = e^{2 pi i a/16}
        const float W16c[8] = {1.f, 0.92387953251f, 0.70710678119f, 0.38268343236f,
                               0.f, -0.38268343236f, -0.70710678119f, -0.92387953251f};
        const float W16s[8] = {0.f, 0.38268343236f, 0.70710678119f, 0.92387953251f,
                               1.f, 0.92387953251f, 0.70710678119f, 0.38268343236f};
        cpx C[8];
        #pragma unroll
        for (int a = 0; a < 8; ++a){
            cpx w  = cmul(make_float2(W16c[a], W16s[a]), es);  // e^{+i th}, th=2pi k/8192
            cpx wc = make_float2(w.x, -w.y);
            cpx Zb = vb[7 - a];                                // Z[4096-k]
            cpx E  = make_float2(0.5f*(va[a].x + Zb.x), 0.5f*(va[a].y - Zb.y));
            cpx D  = make_float2(0.5f*(va[a].x - Zb.x), 0.5f*(va[a].y + Zb.y));
            C[a] = csub(cmul(wc, D), cmul(w, E));
        }
        if (tid == 0) C[0] = make_float2(0.f, 0.f);            // H[0] = 0
        dft8_inv(C);
        #pragma unroll
        for (int a = 0; a < 8; ++a) sdat[slotf(8*tid + a)] = C[a];
    }
    __syncthreads();

    inv_stage8<64 >(sdat, tid); __syncthreads();
    inv_stage8<512>(sdat, tid); __syncthreads();

    // ---------- Final inv L=4096 (regs) fused with epilogue ----------
    const int   first = s_first;
    const int   last  = s_last;
    const float mean  = s_mean;
    const float invM  = 1.0f/4096.0f;
    const float2* lr2 = (const float2*)lab_r;
    const float2* li2 = (const float2*)lab_i;
    float acc = 0.f;
    cpx y[8];
    {
        #pragma unroll
        for (int m = 0; m < 8; ++m) y[m] = sdat[slotf(tid + 512*m)];
        cpx w1 = twf((float)tid * (1.0f/4096.0f));
        cpx w2 = cmul(w1,w1), w3 = cmul(w2,w1), w4 = cmul(w2,w2);
        cpx w5 = cmul(w4,w1), w6 = cmul(w3,w3), w7 = cmul(w4,w3);
        y[1]=cmul(y[1],w1); y[2]=cmul(y[2],w2); y[3]=cmul(y[3],w3);
        y[4]=cmul(y[4],w4); y[5]=cmul(y[5],w5); y[6]=cmul(y[6],w6); y[7]=cmul(y[7],w7);
        dft8_inv(y);
    }
    #pragma unroll
    for (int m = 0; m < 8; ++m){
        int tt = tid + 512*m;                  // c[tt] = h[2tt] + i h[2tt+1]
        float2 lrv = lr2[tt];
        float2 liv = li2[tt];
        float pi0 = y[m].x * invM, pi1 = y[m].y * invM;
        float pr0 = zv[m].x - mean, pr1 = zv[m].y - mean;
        int n = 2 * tt;
        {
            float dr = pr0 - lrv.x, di = pi0 - liv.x;
            acc = fmaf(dr, dr, acc);
            acc = fmaf(di, di, acc);
            float dint = fmaf(pr0, pr0, pi0*pi0) - fmaf(lrv.x, lrv.x, liv.x*liv.x);
            acc = fmaf(dint, dint, acc);
            if (n >= first && n < last){
                float dph = fast_atan2(pi0, pr0) - fast_atan2(liv.x, lrv.x);
                acc = fmaf(dph, dph, acc);
            }
        }
        {
            float dr = pr1 - lrv.y, di = pi1 - liv.y;
            acc = fmaf(dr, dr, acc);
            acc = fmaf(di, di, acc);
            float dint = fmaf(pr1, pr1, pi1*pi1) - fmaf(lrv.y, lrv.y, liv.y*liv.y);
            acc = fmaf(dint, dint, acc);
            if (n + 1 >= first && n + 1 < last){
                float dph = fast_atan2(pi1, pr1) - fast_atan2(liv.y, lrv.y);
                acc = fmaf(dph, dph, acc);
            }
        }
    }
    #pragma unroll
    for (int off = 32; off; off >>= 1) acc += __shfl_down(acc, off);
    if (lane == 0) swsum[wid] = acc;
    __syncthreads();
    if (tid == 0){
        float t = 0.f;
        for (int w = 0; w < 8; ++w) t += swsum[w];
        mse_per[row] = t * (1.0f/8192.0f) * 0.25f;   // /N /MSE_W_SUM
    }
}

__global__ __launch_bounds__(512) void pulse_final_kernel(
    const float* __restrict__ mse_per, float* __restrict__ out)
{
    const int tid = threadIdx.x;
    double v = 0.0;
    if (tid < NROWS) v = (double)(NROWS - tid) * (double)mse_per[tid];
    #pragma unroll
    for (int off = 32; off; off >>= 1) v += __shfl_down(v, off);
    __shared__ double lds[8];
    const int lane = tid & 63, wid = tid >> 6;
    if (lane == 0) lds[wid] = v;
    __syncthreads();
    if (tid == 0){
        double t = 0.0;
        for (int i = 0; i < 8; ++i) t += lds[i];
        out[0] = (float)(t / (double)NROWS);
    }
}

extern "C" void kernel_launch(void* const* d_in, const int* in_sizes, int n_in,
                              void* d_out, int out_size, void* d_ws, size_t ws_size,
                              hipStream_t stream) {
    const float* pred  = (const float*)d_in[0];   // (512, 8192)  f32
    const float* label = (const float*)d_in[1];   // (512, 16384) f32
    float* mse_per = (float*)d_ws;                // 512 floats scratch
    float* out     = (float*)d_out;               // 1 float

    pulse_row_kernel<<<NROWS, THREADS, 0, stream>>>(pred, label, mse_per);
    pulse_final_kernel<<<1, 512, 0, stream>>>(mse_per, out);
}